// Round 2
// baseline (574.109 us; speedup 1.0000x reference)
//
#include <hip/hip_runtime.h>
#include <hip/hip_bf16.h>

// BlockSparseLinear: out[N,OUT] = x[N,IN] . (W * blockmask)^T + bias
// N=8192, IN=4096, OUT=4096, BLOCKSIZE=32, mask (128,128) int32 {0,1}
//
// Round 6: 256x256 tile, BK=32 (1 mask col per K-tile), 4 LDS buffers,
// depth-3 counted pipeline (vmcnt(8) per tile, never 0 in loop), ONE
// barrier per K-tile (hazard proof below), setprio around the 32-MFMA
// cluster, pair-interleaved XOR LDS layout (conflict-free ds_read_b128
// with linear global_load_lds destinations), bijective XCD swizzle.
//
// Buffer hazard proof (4 buffers, read t&3, DMA in flight for t+1,t+2,t+3):
//   - writes at tile t target (t+3)&3 == (t-1)&3: all waves finished
//     reading buf t-1 before the barrier at top of tile t.
//   - in-flight DMA bufs {t+1,t+2,t+3}&3 are all distinct from read buf t&3.
//   - vmcnt(8) at top of tile t drains tile t's 4 loads (12 outstanding -> 8),
//     leaving tiles t+1,t+2 in flight: issue-to-wait distance = 3 tiles.

using bf16 = __hip_bfloat16;
typedef __attribute__((ext_vector_type(8))) short short8;   // 8 x bf16
typedef __attribute__((ext_vector_type(4))) short short4_t; // 4 x bf16
typedef __attribute__((ext_vector_type(4))) float f32x4;    // MFMA accumulator

#define N_ROWS 8192
#define IN     4096
#define OUT    4096
#define KB     128      // mask cols (IN/32)

#define BM 256
#define BO 256
#define BK 32
#define NT (IN / BK)    // 128 K-tiles
#define NBUF 4

__device__ __forceinline__ short4_t cvt4_bf16(float a, float b, float c, float d) {
    union { short4_t s; bf16 h[4]; } u;
    u.h[0] = __float2bfloat16(a);
    u.h[1] = __float2bfloat16(b);
    u.h[2] = __float2bfloat16(c);
    u.h[3] = __float2bfloat16(d);
    return u.s;
}

// ---------------- Fused convert: X fp32->bf16 ; W fp32->bf16 masked ----------
__global__ __launch_bounds__(256)
void cvt_kernel(const float* __restrict__ X, const float* __restrict__ W,
                const int* __restrict__ mask,
                bf16* __restrict__ Xb, bf16* __restrict__ Wb) {
    int b = blockIdx.x;
    if (b < 32768) {
        size_t i = ((size_t)b * 256 + threadIdx.x) * 4;
        float4 d = *(const float4*)(X + i);
        *(short4_t*)(Xb + i) = cvt4_bf16(d.x, d.y, d.z, d.w);
    } else {
        size_t i = ((size_t)(b - 32768) * 256 + threadIdx.x) * 4;
        int row = (int)(i >> 12);          // /IN
        int col = (int)(i & 4095);         // %IN
        int mv  = mask[(row >> 5) * KB + (col >> 5)];
        short4_t p = {};
        if (mv != 0) {
            float4 d = *(const float4*)(W + i);
            p = cvt4_bf16(d.x, d.y, d.z, d.w);
        }
        *(short4_t*)(Wb + i) = p;
    }
}

// 16B global->LDS direct (width 16)
#define GLD(srcp, dstp) __builtin_amdgcn_global_load_lds(                     \
        (const __attribute__((address_space(1))) void*)(srcp),                \
        (__attribute__((address_space(3))) void*)(dstp), 16, 0, 0)

__global__ __launch_bounds__(512, 2)
void bsl_gemm256_kernel(const bf16* __restrict__ Xb, const bf16* __restrict__ Wb,
                        const float* __restrict__ bias, const int* __restrict__ mask,
                        float* __restrict__ out)
{
    __shared__ bf16 sA[NBUF][BM * BK];   // 4 x 16 KB
    __shared__ bf16 sB[NBUF][BO * BK];   // 4 x 16 KB
    __shared__ int  sMask[8 * KB];       // 4 KB

    // bijective XCD swizzle: XCD k -> logical ids [k*64, k*64+64): o-tiles
    // {2k, 2k+1} (2 B-panels = 4 MB, L2-resident), all 32 m-tiles (A streams).
    const int bid = blockIdx.x;
    const int id  = (bid & 7) * 64 + (bid >> 3);
    const int o0  = (id >> 5) * BO;
    const int m0  = (id & 31) * BM;

    const int tid  = threadIdx.x;
    const int wave = tid >> 6;
    const int lane = tid & 63;
    const int wr   = wave >> 2;        // 0..1  m-dim (rows wr*128..+127)
    const int wc   = wave & 3;         // 0..3  o-dim (cols wc*64..+63)

    const int lm = lane & 15;          // fragment row
    const int q  = lane >> 4;          // 0..3 -> 8-elem chunk within K=32
    // pair-interleaved XOR layout: phys(r,c) = (r>>1)*128
    //                        + (((c ^ ((r>>1)&3)) << 1 | (r&1)) << 4)
    // frag-read byte offset within a 16-row block (uniform across blocks):
    const int fb = (lm >> 1) * 128 + ((((q ^ ((lm >> 1) & 3)) << 1) | (lm & 1)) << 4);

    // staging: lane -> (row-in-16-block, logical chunk); dest stays linear.
    const int rp  = lane >> 3;                   // 0..7 row-pair
    const int sub = lane & 7;
    const int sc  = (sub >> 1) ^ (rp & 3);       // logical chunk 0..3
    const int rib = rp * 2 + (sub & 1);          // row within block 0..15

    const bf16* srcA0 = Xb + (size_t)(m0 + wave * 16 + rib) * IN + sc * 8;
    const bf16* srcA1 = srcA0 + (size_t)128 * IN;
    const bf16* srcB0 = Wb + (size_t)(o0 + wave * 16 + rib) * IN + sc * 8;
    const bf16* srcB1 = srcB0 + (size_t)128 * IN;
    const int dst0 = (wave * 16) * 64;           // byte offset in buffer
    const int dst1 = (128 + wave * 16) * 64;

    for (int i = tid; i < 8 * KB; i += 512)
        sMask[i] = mask[(o0 >> 5) * KB + i];

    // ---- prologue: stage tiles 0..2, single full drain ----
    #pragma unroll
    for (int t = 0; t < 3; ++t) {
        const int k = t * BK;
        GLD(srcA0 + k, (char*)sA[t] + dst0);
        GLD(srcA1 + k, (char*)sA[t] + dst1);
        GLD(srcB0 + k, (char*)sB[t] + dst0);
        GLD(srcB1 + k, (char*)sB[t] + dst1);
    }
    __syncthreads();   // publishes sMask + tiles 0..2 (only vmcnt(0) drain)

    f32x4 acc[8][4] = {};
    const int mr0 = (wc * 2) * KB;       // mask row for j=0,1
    const int mr1 = (wc * 2 + 1) * KB;   // mask row for j=2,3

    for (int t = 0; t < NT; ++t) {
        asm volatile("s_waitcnt vmcnt(8)" ::: "memory");  // tile t landed
        __builtin_amdgcn_s_barrier();

        const char* pA = (const char*)sA[t & 3];
        const char* pB = (const char*)sB[t & 3];
        char* nA = (char*)sA[(t + 3) & 3];
        char* nB = (char*)sB[(t + 3) & 3];
        int tn = t + 3; if (tn >= NT) tn -= NT;   // dummy wrap keeps counts uniform
        const int kN = tn * BK;

        // issue tile t+3 staging first (max latency cover)
        GLD(srcA0 + kN, nA + dst0);
        GLD(srcA1 + kN, nA + dst1);
        GLD(srcB0 + kN, nB + dst0);
        GLD(srcB1 + kN, nB + dst1);

        const int mv0 = __builtin_amdgcn_readfirstlane(sMask[mr0 + t]);
        const int mv1 = __builtin_amdgcn_readfirstlane(sMask[mr1 + t]);

        short8 af[8], b0[2], b1[2];
        if (mv0 | mv1) {
            #pragma unroll
            for (int i = 0; i < 8; ++i)
                af[i] = *(const short8*)(pA + wr * 8192 + i * 1024 + fb);
        }
        if (mv0) {
            b0[0] = *(const short8*)(pB + wc * 4096 + 0 * 1024 + fb);
            b0[1] = *(const short8*)(pB + wc * 4096 + 1 * 1024 + fb);
        }
        if (mv1) {
            b1[0] = *(const short8*)(pB + wc * 4096 + 2 * 1024 + fb);
            b1[1] = *(const short8*)(pB + wc * 4096 + 3 * 1024 + fb);
        }
        __builtin_amdgcn_s_setprio(1);
        if (mv0) {
            #pragma unroll
            for (int i = 0; i < 8; ++i) {
                acc[i][0] = __builtin_amdgcn_mfma_f32_16x16x32_bf16(af[i], b0[0], acc[i][0], 0, 0, 0);
                acc[i][1] = __builtin_amdgcn_mfma_f32_16x16x32_bf16(af[i], b0[1], acc[i][1], 0, 0, 0);
            }
        }
        if (mv1) {
            #pragma unroll
            for (int i = 0; i < 8; ++i) {
                acc[i][2] = __builtin_amdgcn_mfma_f32_16x16x32_bf16(af[i], b1[0], acc[i][2], 0, 0, 0);
                acc[i][3] = __builtin_amdgcn_mfma_f32_16x16x32_bf16(af[i], b1[1], acc[i][3], 0, 0, 0);
            }
        }
        __builtin_amdgcn_s_setprio(0);
        __builtin_amdgcn_sched_barrier(0);   // no code motion across tile boundary
    }

    asm volatile("s_waitcnt vmcnt(0)" ::: "memory");  // no pending LDS DMA at end

    // ---- epilogue: C/D layout col=lane&15, row=(lane>>4)*4+reg; fp32 out ----
    const int rbase = (lane >> 4) * 4;
    const int ccol  = lane & 15;
    #pragma unroll
    for (int j = 0; j < 4; ++j) {
        int o = o0 + wc * 64 + j * 16 + ccol;
        float bv = bias[o];
        #pragma unroll
        for (int i = 0; i < 8; ++i) {
            #pragma unroll
            for (int r = 0; r < 4; ++r) {
                int m = m0 + wr * 128 + i * 16 + rbase + r;
                out[(size_t)m * OUT + o] = acc[i][j][r] + bv;
            }
        }
    }
}

// ---------------- Fallback (round-2 single-pass, known-good) ----------------
#define FBM 128
#define FBO 128
#define FBK 64
#define LDK (FBK + 8)
__global__ __launch_bounds__(256, 2)
void bsl_fallback_kernel(const float* __restrict__ X, const float* __restrict__ W,
                         const float* __restrict__ bias, const int* __restrict__ mask,
                         float* __restrict__ out)
{
    __shared__ bf16 sA[FBM * LDK];
    __shared__ bf16 sB[FBO * LDK];
    const int tid = threadIdx.x;
    const int m0 = blockIdx.x * FBM, o0 = blockIdx.y * FBO;
    const int wave = tid >> 6, lane = tid & 63;
    const int wm = (wave & 1) * 64, wo = (wave >> 1) * 64;
    const int lm = lane & 15, lk = (lane >> 4) * 8;
    f32x4 acc[4][4] = {};
    for (int k0 = 0; k0 < IN; k0 += FBK) {
        #pragma unroll
        for (int v = 0; v < 8; ++v) {
            int e = (v * 256 + tid) * 4, row = e >> 6, col = e & 63;
            float4 d = *(const float4*)(X + (size_t)(m0 + row) * IN + (k0 + col));
            *(short4_t*)(sA + row * LDK + col) = cvt4_bf16(d.x, d.y, d.z, d.w);
        }
        #pragma unroll
        for (int v = 0; v < 8; ++v) {
            int e = (v * 256 + tid) * 4, row = e >> 6, col = e & 63;
            int mv = mask[((o0 + row) >> 5) * KB + ((k0 + col) >> 5)];
            short4_t p = {};
            if (mv != 0) {
                float4 d = *(const float4*)(W + (size_t)(o0 + row) * IN + (k0 + col));
                p = cvt4_bf16(d.x, d.y, d.z, d.w);
            }
            *(short4_t*)(sB + row * LDK + col) = p;
        }
        __syncthreads();
        #pragma unroll
        for (int kk = 0; kk < FBK; kk += 32) {
            short8 af[4], bfr[4];
            #pragma unroll
            for (int i = 0; i < 4; ++i)
                af[i] = *(const short8*)(sA + (wm + i * 16 + lm) * LDK + kk + lk);
            #pragma unroll
            for (int j = 0; j < 4; ++j)
                bfr[j] = *(const short8*)(sB + (wo + j * 16 + lm) * LDK + kk + lk);
            #pragma unroll
            for (int i = 0; i < 4; ++i)
                #pragma unroll
                for (int j = 0; j < 4; ++j)
                    acc[i][j] = __builtin_amdgcn_mfma_f32_16x16x32_bf16(
                        af[i], bfr[j], acc[i][j], 0, 0, 0);
        }
        __syncthreads();
    }
    const int rbase = (lane >> 4) * 4, ccol = lane & 15;
    #pragma unroll
    for (int j = 0; j < 4; ++j) {
        int o = o0 + wo + j * 16 + ccol;
        float bv = bias[o];
        #pragma unroll
        for (int i = 0; i < 4; ++i)
            #pragma unroll
            for (int r = 0; r < 4; ++r)
                out[(size_t)(m0 + wm + i * 16 + rbase + r) * OUT + o] = acc[i][j][r] + bv;
    }
}

extern "C" void kernel_launch(void* const* d_in, const int* in_sizes, int n_in,
                              void* d_out, int out_size, void* d_ws, size_t ws_size,
                              hipStream_t stream) {
    const float* x    = (const float*)d_in[0];   // (8192, 4096) fp32
    const float* w    = (const float*)d_in[1];   // (4096, 4096) fp32
    const float* bias = (const float*)d_in[2];   // (4096,) fp32
    const int*   mask = (const int*)  d_in[3];   // (128, 128) int32
    float* out = (float*)d_out;                  // (8192, 4096) fp32

    const size_t xb_bytes = (size_t)N_ROWS * IN * sizeof(bf16);  // 64 MB
    const size_t wb_bytes = (size_t)OUT * IN * sizeof(bf16);     // 32 MB

    if (ws_size >= xb_bytes + wb_bytes) {
        bf16* xb = (bf16*)d_ws;
        bf16* wb = (bf16*)((char*)d_ws + xb_bytes);
        const int xblk = (int)((N_ROWS * (size_t)IN) / 1024);    // 32768
        const int wblk = (int)((OUT * (size_t)IN) / 1024);       // 16384
        cvt_kernel<<<xblk + wblk, 256, 0, stream>>>(x, w, mask, xb, wb);
        bsl_gemm256_kernel<<<512, 512, 0, stream>>>(xb, wb, bias, mask, out);
    } else {
        dim3 grid(N_ROWS / FBM, OUT / FBO);
        bsl_fallback_kernel<<<grid, 256, 0, stream>>>(x, w, bias, mask, out);
    }
}

// Round 3
// 551.529 us; speedup vs baseline: 1.0409x; 1.0409x over previous
//
#include <hip/hip_runtime.h>
#include <hip/hip_bf16.h>

// BlockSparseLinear: out[N,OUT] = x[N,IN] . (W * blockmask)^T + bias
// N=8192, IN=4096, OUT=4096, BLOCKSIZE=32, mask (128,128) int32 {0,1}
//
// Round 7: round-6 engine (256x256 tile, BK=32, 4 LDS buffers, depth-3
// counted pipeline vmcnt(8), ONE barrier per K-tile, pair-interleaved XOR
// LDS layout, setprio) with the block->(o,m) mapping reverted to round-5's
// natural grid (x = o-tile fast, y = m-tile slow).
//
// Why: round-6's per-XCD o-panel swizzle made each XCD stream the entire
// 64 MB Xb unaligned with the others -> FETCH_SIZE doubled 300->610 MB and
// the kernel regressed 246->336 us despite higher sustained BW (2.33 TB/s).
// Natural order launches all 16 o-tiles of one m-tile back-to-back, so the
// A-panel is fetched once and L3-shared chip-wide (round-5 measured 300 MB).
//
// Buffer hazard proof (4 buffers, read t&3, DMA in flight for t+1,t+2,t+3):
//   - writes at tile t target (t+3)&3 == (t-1)&3: all waves finished
//     reading buf t-1 before the barrier at top of tile t.
//   - in-flight DMA bufs {t+1,t+2,t+3}&3 are all distinct from read buf t&3.
//   - vmcnt(8) at top of tile t drains tile t's 4 loads (12 outstanding -> 8),
//     leaving tiles t+1,t+2 in flight: issue-to-wait distance = 3 tiles.

using bf16 = __hip_bfloat16;
typedef __attribute__((ext_vector_type(8))) short short8;   // 8 x bf16
typedef __attribute__((ext_vector_type(4))) short short4_t; // 4 x bf16
typedef __attribute__((ext_vector_type(4))) float f32x4;    // MFMA accumulator

#define N_ROWS 8192
#define IN     4096
#define OUT    4096
#define KB     128      // mask cols (IN/32)

#define BM 256
#define BO 256
#define BK 32
#define NT (IN / BK)    // 128 K-tiles
#define NBUF 4

__device__ __forceinline__ short4_t cvt4_bf16(float a, float b, float c, float d) {
    union { short4_t s; bf16 h[4]; } u;
    u.h[0] = __float2bfloat16(a);
    u.h[1] = __float2bfloat16(b);
    u.h[2] = __float2bfloat16(c);
    u.h[3] = __float2bfloat16(d);
    return u.s;
}

// ---------------- Fused convert: X fp32->bf16 ; W fp32->bf16 masked ----------
__global__ __launch_bounds__(256)
void cvt_kernel(const float* __restrict__ X, const float* __restrict__ W,
                const int* __restrict__ mask,
                bf16* __restrict__ Xb, bf16* __restrict__ Wb) {
    int b = blockIdx.x;
    if (b < 32768) {
        size_t i = ((size_t)b * 256 + threadIdx.x) * 4;
        float4 d = *(const float4*)(X + i);
        *(short4_t*)(Xb + i) = cvt4_bf16(d.x, d.y, d.z, d.w);
    } else {
        size_t i = ((size_t)(b - 32768) * 256 + threadIdx.x) * 4;
        int row = (int)(i >> 12);          // /IN
        int col = (int)(i & 4095);         // %IN
        int mv  = mask[(row >> 5) * KB + (col >> 5)];
        short4_t p = {};
        if (mv != 0) {
            float4 d = *(const float4*)(W + i);
            p = cvt4_bf16(d.x, d.y, d.z, d.w);
        }
        *(short4_t*)(Wb + i) = p;
    }
}

// 16B global->LDS direct (width 16)
#define GLD(srcp, dstp) __builtin_amdgcn_global_load_lds(                     \
        (const __attribute__((address_space(1))) void*)(srcp),                \
        (__attribute__((address_space(3))) void*)(dstp), 16, 0, 0)

__global__ __launch_bounds__(512, 2)
void bsl_gemm256_kernel(const bf16* __restrict__ Xb, const bf16* __restrict__ Wb,
                        const float* __restrict__ bias, const int* __restrict__ mask,
                        float* __restrict__ out)
{
    __shared__ bf16 sA[NBUF][BM * BK];   // 4 x 16 KB
    __shared__ bf16 sB[NBUF][BO * BK];   // 4 x 16 KB
    __shared__ int  sMask[8 * KB];       // 4 KB

    // round-5 natural mapping: x = o-tile (fast), y = m-tile (slow).
    // Consecutive blocks share one A-panel chip-wide -> L3 dedups A fetches.
    const int o0 = blockIdx.x * BO;
    const int m0 = blockIdx.y * BM;

    const int tid  = threadIdx.x;
    const int wave = tid >> 6;
    const int lane = tid & 63;
    const int wr   = wave >> 2;        // 0..1  m-dim (rows wr*128..+127)
    const int wc   = wave & 3;         // 0..3  o-dim (cols wc*64..+63)

    const int lm = lane & 15;          // fragment row
    const int q  = lane >> 4;          // 0..3 -> 8-elem chunk within K=32
    // pair-interleaved XOR layout: phys(r,c) = (r>>1)*128
    //                        + (((c ^ ((r>>1)&3)) << 1 | (r&1)) << 4)
    // frag-read byte offset within a 16-row block (uniform across blocks):
    const int fb = (lm >> 1) * 128 + ((((q ^ ((lm >> 1) & 3)) << 1) | (lm & 1)) << 4);

    // staging: lane -> (row-in-16-block, logical chunk); dest stays linear.
    const int rp  = lane >> 3;                   // 0..7 row-pair
    const int sub = lane & 7;
    const int sc  = (sub >> 1) ^ (rp & 3);       // logical chunk 0..3
    const int rib = rp * 2 + (sub & 1);          // row within block 0..15

    const bf16* srcA0 = Xb + (size_t)(m0 + wave * 16 + rib) * IN + sc * 8;
    const bf16* srcA1 = srcA0 + (size_t)128 * IN;
    const bf16* srcB0 = Wb + (size_t)(o0 + wave * 16 + rib) * IN + sc * 8;
    const bf16* srcB1 = srcB0 + (size_t)128 * IN;
    const int dst0 = (wave * 16) * 64;           // byte offset in buffer
    const int dst1 = (128 + wave * 16) * 64;

    for (int i = tid; i < 8 * KB; i += 512)
        sMask[i] = mask[(o0 >> 5) * KB + i];

    // ---- prologue: stage tiles 0..2, single full drain ----
    #pragma unroll
    for (int t = 0; t < 3; ++t) {
        const int k = t * BK;
        GLD(srcA0 + k, (char*)sA[t] + dst0);
        GLD(srcA1 + k, (char*)sA[t] + dst1);
        GLD(srcB0 + k, (char*)sB[t] + dst0);
        GLD(srcB1 + k, (char*)sB[t] + dst1);
    }
    __syncthreads();   // publishes sMask + tiles 0..2 (only vmcnt(0) drain)

    f32x4 acc[8][4] = {};
    const int mr0 = (wc * 2) * KB;       // mask row for j=0,1
    const int mr1 = (wc * 2 + 1) * KB;   // mask row for j=2,3

    for (int t = 0; t < NT; ++t) {
        asm volatile("s_waitcnt vmcnt(8)" ::: "memory");  // tile t landed
        __builtin_amdgcn_s_barrier();

        const char* pA = (const char*)sA[t & 3];
        const char* pB = (const char*)sB[t & 3];
        char* nA = (char*)sA[(t + 3) & 3];
        char* nB = (char*)sB[(t + 3) & 3];
        int tn = t + 3; if (tn >= NT) tn -= NT;   // dummy wrap keeps counts uniform
        const int kN = tn * BK;

        // issue tile t+3 staging first (max latency cover)
        GLD(srcA0 + kN, nA + dst0);
        GLD(srcA1 + kN, nA + dst1);
        GLD(srcB0 + kN, nB + dst0);
        GLD(srcB1 + kN, nB + dst1);

        const int mv0 = __builtin_amdgcn_readfirstlane(sMask[mr0 + t]);
        const int mv1 = __builtin_amdgcn_readfirstlane(sMask[mr1 + t]);

        short8 af[8], b0[2], b1[2];
        if (mv0 | mv1) {
            #pragma unroll
            for (int i = 0; i < 8; ++i)
                af[i] = *(const short8*)(pA + wr * 8192 + i * 1024 + fb);
        }
        if (mv0) {
            b0[0] = *(const short8*)(pB + wc * 4096 + 0 * 1024 + fb);
            b0[1] = *(const short8*)(pB + wc * 4096 + 1 * 1024 + fb);
        }
        if (mv1) {
            b1[0] = *(const short8*)(pB + wc * 4096 + 2 * 1024 + fb);
            b1[1] = *(const short8*)(pB + wc * 4096 + 3 * 1024 + fb);
        }
        __builtin_amdgcn_s_setprio(1);
        if (mv0) {
            #pragma unroll
            for (int i = 0; i < 8; ++i) {
                acc[i][0] = __builtin_amdgcn_mfma_f32_16x16x32_bf16(af[i], b0[0], acc[i][0], 0, 0, 0);
                acc[i][1] = __builtin_amdgcn_mfma_f32_16x16x32_bf16(af[i], b0[1], acc[i][1], 0, 0, 0);
            }
        }
        if (mv1) {
            #pragma unroll
            for (int i = 0; i < 8; ++i) {
                acc[i][2] = __builtin_amdgcn_mfma_f32_16x16x32_bf16(af[i], b1[0], acc[i][2], 0, 0, 0);
                acc[i][3] = __builtin_amdgcn_mfma_f32_16x16x32_bf16(af[i], b1[1], acc[i][3], 0, 0, 0);
            }
        }
        __builtin_amdgcn_s_setprio(0);
        __builtin_amdgcn_sched_barrier(0);   // no code motion across tile boundary
    }

    asm volatile("s_waitcnt vmcnt(0)" ::: "memory");  // no pending LDS DMA at end

    // ---- epilogue: C/D layout col=lane&15, row=(lane>>4)*4+reg; fp32 out ----
    const int rbase = (lane >> 4) * 4;
    const int ccol  = lane & 15;
    #pragma unroll
    for (int j = 0; j < 4; ++j) {
        int o = o0 + wc * 64 + j * 16 + ccol;
        float bv = bias[o];
        #pragma unroll
        for (int i = 0; i < 8; ++i) {
            #pragma unroll
            for (int r = 0; r < 4; ++r) {
                int m = m0 + wr * 128 + i * 16 + rbase + r;
                out[(size_t)m * OUT + o] = acc[i][j][r] + bv;
            }
        }
    }
}

// ---------------- Fallback (round-2 single-pass, known-good) ----------------
#define FBM 128
#define FBO 128
#define FBK 64
#define LDK (FBK + 8)
__global__ __launch_bounds__(256, 2)
void bsl_fallback_kernel(const float* __restrict__ X, const float* __restrict__ W,
                         const float* __restrict__ bias, const int* __restrict__ mask,
                         float* __restrict__ out)
{
    __shared__ bf16 sA[FBM * LDK];
    __shared__ bf16 sB[FBO * LDK];
    const int tid = threadIdx.x;
    const int m0 = blockIdx.x * FBM, o0 = blockIdx.y * FBO;
    const int wave = tid >> 6, lane = tid & 63;
    const int wm = (wave & 1) * 64, wo = (wave >> 1) * 64;
    const int lm = lane & 15, lk = (lane >> 4) * 8;
    f32x4 acc[4][4] = {};
    for (int k0 = 0; k0 < IN; k0 += FBK) {
        #pragma unroll
        for (int v = 0; v < 8; ++v) {
            int e = (v * 256 + tid) * 4, row = e >> 6, col = e & 63;
            float4 d = *(const float4*)(X + (size_t)(m0 + row) * IN + (k0 + col));
            *(short4_t*)(sA + row * LDK + col) = cvt4_bf16(d.x, d.y, d.z, d.w);
        }
        #pragma unroll
        for (int v = 0; v < 8; ++v) {
            int e = (v * 256 + tid) * 4, row = e >> 6, col = e & 63;
            int mv = mask[((o0 + row) >> 5) * KB + ((k0 + col) >> 5)];
            short4_t p = {};
            if (mv != 0) {
                float4 d = *(const float4*)(W + (size_t)(o0 + row) * IN + (k0 + col));
                p = cvt4_bf16(d.x, d.y, d.z, d.w);
            }
            *(short4_t*)(sB + row * LDK + col) = p;
        }
        __syncthreads();
        #pragma unroll
        for (int kk = 0; kk < FBK; kk += 32) {
            short8 af[4], bfr[4];
            #pragma unroll
            for (int i = 0; i < 4; ++i)
                af[i] = *(const short8*)(sA + (wm + i * 16 + lm) * LDK + kk + lk);
            #pragma unroll
            for (int j = 0; j < 4; ++j)
                bfr[j] = *(const short8*)(sB + (wo + j * 16 + lm) * LDK + kk + lk);
            #pragma unroll
            for (int i = 0; i < 4; ++i)
                #pragma unroll
                for (int j = 0; j < 4; ++j)
                    acc[i][j] = __builtin_amdgcn_mfma_f32_16x16x32_bf16(
                        af[i], bfr[j], acc[i][j], 0, 0, 0);
        }
        __syncthreads();
    }
    const int rbase = (lane >> 4) * 4, ccol = lane & 15;
    #pragma unroll
    for (int j = 0; j < 4; ++j) {
        int o = o0 + wo + j * 16 + ccol;
        float bv = bias[o];
        #pragma unroll
        for (int i = 0; i < 4; ++i)
            #pragma unroll
            for (int r = 0; r < 4; ++r)
                out[(size_t)(m0 + wm + i * 16 + rbase + r) * OUT + o] = acc[i][j][r] + bv;
    }
}

extern "C" void kernel_launch(void* const* d_in, const int* in_sizes, int n_in,
                              void* d_out, int out_size, void* d_ws, size_t ws_size,
                              hipStream_t stream) {
    const float* x    = (const float*)d_in[0];   // (8192, 4096) fp32
    const float* w    = (const float*)d_in[1];   // (4096, 4096) fp32
    const float* bias = (const float*)d_in[2];   // (4096,) fp32
    const int*   mask = (const int*)  d_in[3];   // (128, 128) int32
    float* out = (float*)d_out;                  // (8192, 4096) fp32

    const size_t xb_bytes = (size_t)N_ROWS * IN * sizeof(bf16);  // 64 MB
    const size_t wb_bytes = (size_t)OUT * IN * sizeof(bf16);     // 32 MB

    if (ws_size >= xb_bytes + wb_bytes) {
        bf16* xb = (bf16*)d_ws;
        bf16* wb = (bf16*)((char*)d_ws + xb_bytes);
        const int xblk = (int)((N_ROWS * (size_t)IN) / 1024);    // 32768
        const int wblk = (int)((OUT * (size_t)IN) / 1024);       // 16384
        cvt_kernel<<<xblk + wblk, 256, 0, stream>>>(x, w, mask, xb, wb);
        dim3 grid(OUT / BO, N_ROWS / BM);        // (16, 32): o fast, m slow
        bsl_gemm256_kernel<<<grid, 512, 0, stream>>>(xb, wb, bias, mask, out);
    } else {
        dim3 grid(N_ROWS / FBM, OUT / FBO);
        bsl_fallback_kernel<<<grid, 256, 0, stream>>>(x, w, bias, mask, out);
    }
}

// Round 5
// 499.566 us; speedup vs baseline: 1.1492x; 1.1040x over previous
//
#include <hip/hip_runtime.h>
#include <hip/hip_bf16.h>

// BlockSparseLinear: out[N,OUT] = x[N,IN] . (W * blockmask)^T + bias
// N=8192, IN=4096, OUT=4096, BLOCKSIZE=32, mask (128,128) int32 {0,1}
//
// Round 8 (resubmit after infra failure): faithful port of the verified
// 256^2 8-phase template (m194-m201): BK=64, 4 phases per K-tile, per-phase
// {ds_read subtile || 1 half-tile GLD stage || barrier || setprio+16-MFMA
// quadrant || barrier}, ONE counted vmcnt(4) per K-tile (never 0 in loop).
// Mask gating per phase = one wave-uniform mask bit (phase = j-pair x
// kk-slice). Round-5's verified chunk^(row&7) LDS swizzle (0 conflicts
// measured). Grid (16,32) o-fast (FETCH 304 MB verified rounds 5/7).
//
// Half-slot ledger (8 slots of 128x64 bf16 = 128 KB; parity = tile&1):
//   stage @ t.P0: B_lo(t+1)  -> slot(B_lo, t+1&1). Prev contents B_lo(t-1):
//                 last read t-1.P0/P1, drained before t-1.P1 MFMA < t.P0. SAFE
//   stage @ t.P1: B_hi(t+1)  -> same argument (B_hi read t-1.P0..P3).    SAFE
//   stage @ t.P3: A_lo/A_hi(t+2) -> slot(A, t&1) holds A(t): last read
//                 issued t.P2, force-drained by lgkmcnt(0) at P2 end,
//                 barrier before P3 GLD issue.                           SAFE
// Per-wave load FIFO per tile: [B(t+1) x4][A(t+2) x4]; vmcnt(4) at tile top
// leaves newest 4 = A(t+2) in flight, forces B(t)+A(t) landed. Leads:
// B_lo 4, B_hi 3, A_lo 6, A_hi 5 phases >= 3 needed for ~900cy HBM latency.
// Prologue stages A(0),B(0),A(1) then full drain (once). Tail: dummy-wrap
// staging keeps vmcnt counts uniform (slots provably dead, ~3% extra bytes).

using bf16 = __hip_bfloat16;
typedef __attribute__((ext_vector_type(8))) short short8;   // 8 x bf16
typedef __attribute__((ext_vector_type(4))) short short4_t; // 4 x bf16
typedef __attribute__((ext_vector_type(4))) float f32x4;    // MFMA accumulator

#define N_ROWS 8192
#define IN     4096
#define OUT    4096
#define KB     128      // mask cols (IN/32)

#define BM 256
#define BO 256
#define BK 64
#define NT (IN / BK)    // 64 K-tiles

__device__ __forceinline__ short4_t cvt4_bf16(float a, float b, float c, float d) {
    union { short4_t s; bf16 h[4]; } u;
    u.h[0] = __float2bfloat16(a);
    u.h[1] = __float2bfloat16(b);
    u.h[2] = __float2bfloat16(c);
    u.h[3] = __float2bfloat16(d);
    return u.s;
}

// ---------------- Fused convert: X fp32->bf16 ; W fp32->bf16 masked ----------
__global__ __launch_bounds__(256)
void cvt_kernel(const float* __restrict__ X, const float* __restrict__ W,
                const int* __restrict__ mask,
                bf16* __restrict__ Xb, bf16* __restrict__ Wb) {
    int b = blockIdx.x;
    if (b < 32768) {
        size_t i = ((size_t)b * 256 + threadIdx.x) * 4;
        float4 d = *(const float4*)(X + i);
        *(short4_t*)(Xb + i) = cvt4_bf16(d.x, d.y, d.z, d.w);
    } else {
        size_t i = ((size_t)(b - 32768) * 256 + threadIdx.x) * 4;
        int row = (int)(i >> 12);          // /IN
        int col = (int)(i & 4095);         // %IN
        int mv  = mask[(row >> 5) * KB + (col >> 5)];
        short4_t p = {};
        if (mv != 0) {
            float4 d = *(const float4*)(W + i);
            p = cvt4_bf16(d.x, d.y, d.z, d.w);
        }
        *(short4_t*)(Wb + i) = p;
    }
}

// 16B global->LDS direct; dest is wave-uniform base + lane*16 (linear).
#define GLD(srcp, dstp) __builtin_amdgcn_global_load_lds(                     \
        (const __attribute__((address_space(1))) void*)(srcp),                \
        (__attribute__((address_space(3))) void*)(dstp), 16, 0, 0)

// Stage one 64-row chunk (v) of half H of a tile: 512 threads x 16B = 8 KB.
// Source row = base + H*128 + V*64 + wave*8 + (lane>>3); source chunk
// pre-swizzled (lane&7)^(lane>>3); dest linear at rows (V*64 + wave*8).
#define STAGE_A(P, H, V, KOFF)                                                \
    GLD(gA + (size_t)((H) * 128 + (V) * 64) * IN + (KOFF),                    \
        (char*)sA[P][H] + ((V) * 64 + wave * 8) * 128)
#define STAGE_B(P, H, V, KOFF)                                                \
    GLD(gB + (size_t)((H) * 128 + (V) * 64) * IN + (KOFF),                    \
        (char*)sB[P][H] + ((V) * 64 + wave * 8) * 128)

// 16-MFMA quadrant: all 8 i-frags x one j-pair (J, J+1).
#define MFMA_J2(J, AF, B0, B1)                                                \
    { _Pragma("unroll") for (int i = 0; i < 8; ++i) {                         \
        acc[i][J]     = __builtin_amdgcn_mfma_f32_16x16x32_bf16(              \
                            AF[i], B0, acc[i][J], 0, 0, 0);                   \
        acc[i][(J)+1] = __builtin_amdgcn_mfma_f32_16x16x32_bf16(              \
                            AF[i], B1, acc[i][(J)+1], 0, 0, 0); } }

__global__ __launch_bounds__(512, 2)
void bsl_gemm256_kernel(const bf16* __restrict__ Xb, const bf16* __restrict__ Wb,
                        const float* __restrict__ bias, const int* __restrict__ mask,
                        float* __restrict__ out)
{
    // [parity][half][128 rows x 64 cols], swizzled chunk = c16 ^ (row&7)
    __shared__ bf16 sA[2][2][128 * 64];   // 64 KB
    __shared__ bf16 sB[2][2][128 * 64];   // 64 KB
    __shared__ int  sMask[8 * KB];        // 4 KB

    const int o0 = blockIdx.x * BO;   // o fast: A-panel L3-shared chip-wide
    const int m0 = blockIdx.y * BM;

    const int tid  = threadIdx.x;
    const int wave = tid >> 6;
    const int lane = tid & 63;
    const int wr   = wave >> 2;        // 0..1  m-half (128 rows)
    const int wc   = wave & 3;         // 0..3  o-quarter (64 cols)

    const int lm = lane & 15;          // fragment row
    const int q  = lane >> 4;          // 0..3 -> 16B chunk within K=32 slice
    const int xm = lm & 7;             // read-side swizzle xor (row&7 == lm&7)
    const int cb0 = ((0 + q) ^ xm) * 16;   // kk=0 chunk byte
    const int cb1 = ((4 + q) ^ xm) * 16;   // kk=1 chunk byte
    const int rowA = lm * 128;                         // + i*2048
    const int rowB = (wc & 1) * 8192 + lm * 128;       // + j*2048

    // staging source (per-lane): row wave*8+(lane>>3), chunk (lane&7)^(lane>>3)
    const int lrow = lane >> 3;
    const int lchk = (lane & 7) ^ lrow;
    const bf16* gA = Xb + (size_t)(m0 + wave * 8 + lrow) * IN + lchk * 8;
    const bf16* gB = Wb + (size_t)(o0 + wave * 8 + lrow) * IN + lchk * 8;

    for (int i = tid; i < 8 * KB; i += 512)
        sMask[i] = mask[(o0 >> 5) * KB + i];

    // ---- prologue: A(0), B(0) parity 0; A(1) parity 1; single full drain ----
    STAGE_A(0, 0, 0, 0);  STAGE_A(0, 0, 1, 0);
    STAGE_A(0, 1, 0, 0);  STAGE_A(0, 1, 1, 0);
    STAGE_B(0, 0, 0, 0);  STAGE_B(0, 0, 1, 0);
    STAGE_B(0, 1, 0, 0);  STAGE_B(0, 1, 1, 0);
    STAGE_A(1, 0, 0, BK); STAGE_A(1, 0, 1, BK);
    STAGE_A(1, 1, 0, BK); STAGE_A(1, 1, 1, BK);
    __syncthreads();   // publishes sMask + tile 0/1 A, tile 0 B (only full drain)

    f32x4 acc[8][4] = {};
    const int mr0 = (wc * 2) * KB;       // mask row for j-pair {0,1}
    const int mr1 = mr0 + KB;            // mask row for j-pair {2,3}

    for (int t = 0; t < NT; ++t) {
        const int c  = t & 1;
        const int cn = c ^ 1;
        const int t1 = (t + 1 < NT) ? t + 1 : 0;          // dummy wrap: keeps
        const int t2 = (t + 2 < NT) ? t + 2 : t + 2 - NT; // vmcnt counts uniform
        const size_t k1 = (size_t)t1 * BK;
        const size_t k2 = (size_t)t2 * BK;

        // ---- tile top: tile t fully landed (newest 4 in flight = A(t+2)) ----
        asm volatile("s_waitcnt vmcnt(4)" ::: "memory");
        __builtin_amdgcn_s_barrier();

        const int mv00 = __builtin_amdgcn_readfirstlane(sMask[mr0 + 2 * t]);
        const int mv10 = __builtin_amdgcn_readfirstlane(sMask[mr1 + 2 * t]);
        const int mv01 = __builtin_amdgcn_readfirstlane(sMask[mr0 + 2 * t + 1]);
        const int mv11 = __builtin_amdgcn_readfirstlane(sMask[mr1 + 2 * t + 1]);

        const char* baseA = (const char*)sA[c][wr];
        const char* baseB = (const char*)sB[c][wc >> 1];
        short8 a[8];

        // ========== P0: quadrant (j 0-1, kk0); stage B_lo(t+1) ==========
        if (mv00 | mv10) {
            #pragma unroll
            for (int i = 0; i < 8; ++i)
                a[i] = *(const short8*)(baseA + i * 2048 + rowA + cb0);
        }
        short8 b00a, b00b;
        if (mv00) {
            b00a = *(const short8*)(baseB + rowB + cb0);
            b00b = *(const short8*)(baseB + rowB + 2048 + cb0);
        }
        STAGE_B(cn, 0, 0, k1); STAGE_B(cn, 0, 1, k1);
        __builtin_amdgcn_s_barrier();
        __builtin_amdgcn_s_setprio(1);
        if (mv00) MFMA_J2(0, a, b00a, b00b);
        __builtin_amdgcn_s_setprio(0);
        __builtin_amdgcn_s_barrier();

        // ========== P1: quadrant (j 2-3, kk0); stage B_hi(t+1) ==========
        short8 b10a, b10b;
        if (mv10) {
            b10a = *(const short8*)(baseB + rowB + 4096 + cb0);
            b10b = *(const short8*)(baseB + rowB + 6144 + cb0);
        }
        STAGE_B(cn, 1, 0, k1); STAGE_B(cn, 1, 1, k1);
        __builtin_amdgcn_s_barrier();
        __builtin_amdgcn_s_setprio(1);
        if (mv10) MFMA_J2(2, a, b10a, b10b);
        __builtin_amdgcn_s_setprio(0);
        __builtin_amdgcn_s_barrier();

        // ========== P2: quadrant (j 0-1, kk1); no stage ==========
        if (mv01 | mv11) {
            #pragma unroll
            for (int i = 0; i < 8; ++i)
                a[i] = *(const short8*)(baseA + i * 2048 + rowA + cb1);
        }
        short8 b01a, b01b;
        if (mv01) {
            b01a = *(const short8*)(baseB + rowB + cb1);
            b01b = *(const short8*)(baseB + rowB + 2048 + cb1);
        }
        __builtin_amdgcn_s_barrier();
        __builtin_amdgcn_s_setprio(1);
        if (mv01) MFMA_J2(0, a, b01a, b01b);
        __builtin_amdgcn_s_setprio(0);
        // guard: P2's a[] ds_reads may be unconsumed here (mv01=0, mv11=1);
        // force-drain before P3 overwrites the A(t) slot via DMA.
        asm volatile("s_waitcnt lgkmcnt(0)" ::: "memory");
        __builtin_amdgcn_s_barrier();

        // ========== P3: quadrant (j 2-3, kk1); stage A_lo+A_hi(t+2) ==========
        short8 b11a, b11b;
        if (mv11) {
            b11a = *(const short8*)(baseB + rowB + 4096 + cb1);
            b11b = *(const short8*)(baseB + rowB + 6144 + cb1);
        }
        STAGE_A(c, 0, 0, k2); STAGE_A(c, 0, 1, k2);
        STAGE_A(c, 1, 0, k2); STAGE_A(c, 1, 1, k2);
        __builtin_amdgcn_s_barrier();
        __builtin_amdgcn_s_setprio(1);
        if (mv11) MFMA_J2(2, a, b11a, b11b);
        __builtin_amdgcn_s_setprio(0);
        // tile-top vmcnt+barrier serves as P3's closing barrier
    }

    asm volatile("s_waitcnt vmcnt(0)" ::: "memory");  // no pending LDS DMA at end

    // ---- epilogue: C/D layout col=lane&15, row=(lane>>4)*4+reg; fp32 out ----
    const int rbase = (lane >> 4) * 4;
    const int ccol  = lane & 15;
    #pragma unroll
    for (int j = 0; j < 4; ++j) {
        int o = o0 + wc * 64 + j * 16 + ccol;
        float bv = bias[o];
        #pragma unroll
        for (int i = 0; i < 8; ++i) {
            #pragma unroll
            for (int r = 0; r < 4; ++r) {
                int m = m0 + wr * 128 + i * 16 + rbase + r;
                out[(size_t)m * OUT + o] = acc[i][j][r] + bv;
            }
        }
    }
}

// ---------------- Fallback (round-2 single-pass, known-good) ----------------
#define FBM 128
#define FBO 128
#define FBK 64
#define LDK (FBK + 8)
__global__ __launch_bounds__(256, 2)
void bsl_fallback_kernel(const float* __restrict__ X, const float* __restrict__ W,
                         const float* __restrict__ bias, const int* __restrict__ mask,
                         float* __restrict__ out)
{
    __shared__ bf16 sA[FBM * LDK];
    __shared__ bf16 sB[FBO * LDK];
    const int tid = threadIdx.x;
    const int m0 = blockIdx.x * FBM, o0 = blockIdx.y * FBO;
    const int wave = tid >> 6, lane = tid & 63;
    const int wm = (wave & 1) * 64, wo = (wave >> 1) * 64;
    const int lm = lane & 15, lk = (lane >> 4) * 8;
    f32x4 acc[4][4] = {};
    for (int k0 = 0; k0 < IN; k0 += FBK) {
        #pragma unroll
        for (int v = 0; v < 8; ++v) {
            int e = (v * 256 + tid) * 4, row = e >> 6, col = e & 63;
            float4 d = *(const float4*)(X + (size_t)(m0 + row) * IN + (k0 + col));
            *(short4_t*)(sA + row * LDK + col) = cvt4_bf16(d.x, d.y, d.z, d.w);
        }
        #pragma unroll
        for (int v = 0; v < 8; ++v) {
            int e = (v * 256 + tid) * 4, row = e >> 6, col = e & 63;
            int mv = mask[((o0 + row) >> 5) * KB + ((k0 + col) >> 5)];
            short4_t p = {};
            if (mv != 0) {
                float4 d = *(const float4*)(W + (size_t)(o0 + row) * IN + (k0 + col));
                p = cvt4_bf16(d.x, d.y, d.z, d.w);
            }
            *(short4_t*)(sB + row * LDK + col) = p;
        }
        __syncthreads();
        #pragma unroll
        for (int kk = 0; kk < FBK; kk += 32) {
            short8 af[4], bfr[4];
            #pragma unroll
            for (int i = 0; i < 4; ++i)
                af[i] = *(const short8*)(sA + (wm + i * 16 + lm) * LDK + kk + lk);
            #pragma unroll
            for (int j = 0; j < 4; ++j)
                bfr[j] = *(const short8*)(sB + (wo + j * 16 + lm) * LDK + kk + lk);
            #pragma unroll
            for (int i = 0; i < 4; ++i)
                #pragma unroll
                for (int j = 0; j < 4; ++j)
                    acc[i][j] = __builtin_amdgcn_mfma_f32_16x16x32_bf16(
                        af[i], bfr[j], acc[i][j], 0, 0, 0);
        }
        __syncthreads();
    }
    const int rbase = (lane >> 4) * 4, ccol = lane & 15;
    #pragma unroll
    for (int j = 0; j < 4; ++j) {
        int o = o0 + wo + j * 16 + ccol;
        float bv = bias[o];
        #pragma unroll
        for (int i = 0; i < 4; ++i)
            #pragma unroll
            for (int r = 0; r < 4; ++r)
                out[(size_t)(m0 + wm + i * 16 + rbase + r) * OUT + o] = acc[i][j][r] + bv;
    }
}

extern "C" void kernel_launch(void* const* d_in, const int* in_sizes, int n_in,
                              void* d_out, int out_size, void* d_ws, size_t ws_size,
                              hipStream_t stream) {
    const float* x    = (const float*)d_in[0];   // (8192, 4096) fp32
    const float* w    = (const float*)d_in[1];   // (4096, 4096) fp32
    const float* bias = (const float*)d_in[2];   // (4096,) fp32
    const int*   mask = (const int*)  d_in[3];   // (128, 128) int32
    float* out = (float*)d_out;                  // (8192, 4096) fp32

    const size_t xb_bytes = (size_t)N_ROWS * IN * sizeof(bf16);  // 64 MB
    const size_t wb_bytes = (size_t)OUT * IN * sizeof(bf16);     // 32 MB

    if (ws_size >= xb_bytes + wb_bytes) {
        bf16* xb = (bf16*)d_ws;
        bf16* wb = (bf16*)((char*)d_ws + xb_bytes);
        const int xblk = (int)((N_ROWS * (size_t)IN) / 1024);    // 32768
        const int wblk = (int)((OUT * (size_t)IN) / 1024);       // 16384
        cvt_kernel<<<xblk + wblk, 256, 0, stream>>>(x, w, mask, xb, wb);
        dim3 grid(OUT / BO, N_ROWS / BM);        // (16, 32): o fast, m slow
        bsl_gemm256_kernel<<<grid, 512, 0, stream>>>(xb, wb, bias, mask, out);
    } else {
        dim3 grid(N_ROWS / FBM, OUT / FBO);
        bsl_fallback_kernel<<<grid, 256, 0, stream>>>(x, w, bias, mask, out);
    }
}

// Round 6
// 496.794 us; speedup vs baseline: 1.1556x; 1.0056x over previous
//
#include <hip/hip_runtime.h>
#include <hip/hip_bf16.h>

// BlockSparseLinear: out[N,OUT] = x[N,IN] . (W * blockmask)^T + bias
// N=8192, IN=4096, OUT=4096, BLOCKSIZE=32, mask (128,128) int32 {0,1}
//
// Round 9: de-synchronized gating. 256x256 tile, BK=64, parity double-buffer
// (128 KB), ONE barrier + ONE vmcnt(0) per K-tile; all mask-gated ds_read /
// MFMA units flow in free per-wave order between barriers (straggler tax
// averages over 4 units/tile instead of per-phase E[max]); all of tile t+1's
// staging issued at the TOP of tile t (full-tile ~2000cy lead >> 900cy HBM
// latency, so the vmcnt(0) is free); B-staging gated per 8-row strip by its
// mask-row pair (p=0.75) - safe because vmcnt(0) tolerates divergent GLD
// counts and dead strips are never read (Wb is pre-zeroed by cvt).
//
// Hazard ledger:
//  - staging at tile t targets ONLY buf c^1 (parity): last readers were
//    tile t-1, whose ds_reads are consumed by MFMAs before that wave reaches
//    the tile-t barrier => no read-vs-DMA race, single barrier suffices.
//  - every ds_read in tile t is consumed by an MFMA in tile t (gates match),
//    so lgkm is drained by data dependence; no explicit lgkmcnt(0) needed.
//  - vmcnt(0) at tile top => tile t fully landed; no counting assumptions.

using bf16 = __hip_bfloat16;
typedef __attribute__((ext_vector_type(8))) short short8;   // 8 x bf16
typedef __attribute__((ext_vector_type(4))) short short4_t; // 4 x bf16
typedef __attribute__((ext_vector_type(4))) float f32x4;    // MFMA accumulator

#define N_ROWS 8192
#define IN     4096
#define OUT    4096
#define KB     128      // mask cols (IN/32)

#define BM 256
#define BO 256
#define BK 64
#define NT (IN / BK)    // 64 K-tiles

__device__ __forceinline__ short4_t cvt4_bf16(float a, float b, float c, float d) {
    union { short4_t s; bf16 h[4]; } u;
    u.h[0] = __float2bfloat16(a);
    u.h[1] = __float2bfloat16(b);
    u.h[2] = __float2bfloat16(c);
    u.h[3] = __float2bfloat16(d);
    return u.s;
}

// ---------------- Fused convert: X fp32->bf16 ; W fp32->bf16 masked ----------
__global__ __launch_bounds__(256)
void cvt_kernel(const float* __restrict__ X, const float* __restrict__ W,
                const int* __restrict__ mask,
                bf16* __restrict__ Xb, bf16* __restrict__ Wb) {
    int b = blockIdx.x;
    if (b < 32768) {
        size_t i = ((size_t)b * 256 + threadIdx.x) * 4;
        float4 d = *(const float4*)(X + i);
        *(short4_t*)(Xb + i) = cvt4_bf16(d.x, d.y, d.z, d.w);
    } else {
        size_t i = ((size_t)(b - 32768) * 256 + threadIdx.x) * 4;
        int row = (int)(i >> 12);          // /IN
        int col = (int)(i & 4095);         // %IN
        int mv  = mask[(row >> 5) * KB + (col >> 5)];
        short4_t p = {};
        if (mv != 0) {
            float4 d = *(const float4*)(W + i);
            p = cvt4_bf16(d.x, d.y, d.z, d.w);
        }
        *(short4_t*)(Wb + i) = p;
    }
}

// 16B global->LDS direct; dest is wave-uniform base + lane*16 (linear).
#define GLD(srcp, dstp) __builtin_amdgcn_global_load_lds(                     \
        (const __attribute__((address_space(1))) void*)(srcp),                \
        (__attribute__((address_space(3))) void*)(dstp), 16, 0, 0)

// Stage one 64-row chunk (V) of half H: 512 threads x 16B = 8 KB.
// Source row = H*128 + V*64 + wave*8 + (lane>>3); source chunk pre-swizzled
// (lane&7)^(lane>>3); dest linear at rows (V*64 + wave*8).
#define STAGE_A(P, H, V, KOFF)                                                \
    GLD(gA + (size_t)((H) * 128 + (V) * 64) * IN + (KOFF),                    \
        (char*)sA[P][H] + ((V) * 64 + wave * 8) * 128)
#define STAGE_B(P, H, V, KOFF)                                                \
    GLD(gB + (size_t)((H) * 128 + (V) * 64) * IN + (KOFF),                    \
        (char*)sB[P][H] + ((V) * 64 + wave * 8) * 128)

// 16-MFMA quadrant: all 8 i-frags x one j-pair (J, J+1).
#define MFMA_J2(J, AF, B0, B1)                                                \
    { _Pragma("unroll") for (int i = 0; i < 8; ++i) {                         \
        acc[i][J]     = __builtin_amdgcn_mfma_f32_16x16x32_bf16(              \
                            AF[i], B0, acc[i][J], 0, 0, 0);                   \
        acc[i][(J)+1] = __builtin_amdgcn_mfma_f32_16x16x32_bf16(              \
                            AF[i], B1, acc[i][(J)+1], 0, 0, 0); } }

__global__ __launch_bounds__(512, 2)
void bsl_gemm256_kernel(const bf16* __restrict__ Xb, const bf16* __restrict__ Wb,
                        const float* __restrict__ bias, const int* __restrict__ mask,
                        float* __restrict__ out)
{
    // [parity][half][128 rows x 64 cols], swizzled chunk = c16 ^ (row&7)
    __shared__ bf16 sA[2][2][128 * 64];   // 64 KB
    __shared__ bf16 sB[2][2][128 * 64];   // 64 KB
    __shared__ int  sMask[8 * KB];        // 4 KB

    const int o0 = blockIdx.x * BO;   // o fast: A-panel L3-shared chip-wide
    const int m0 = blockIdx.y * BM;

    const int tid  = threadIdx.x;
    const int wave = tid >> 6;
    const int lane = tid & 63;
    const int wr   = wave >> 2;        // 0..1  m-half (128 rows)
    const int wc   = wave & 3;         // 0..3  o-quarter (64 cols)

    const int lm = lane & 15;          // fragment row
    const int q  = lane >> 4;          // 0..3 -> 16B chunk within K=32 slice
    const int xm = lm & 7;             // read-side swizzle xor (row&7 == lm&7)
    const int cb0 = ((0 + q) ^ xm) * 16;   // kk=0 chunk byte
    const int cb1 = ((4 + q) ^ xm) * 16;   // kk=1 chunk byte
    const int rowA = lm * 128;                         // + i*2048
    const int rowB = (wc & 1) * 8192 + lm * 128;       // + j*2048

    // staging source (per-lane): row wave*8+(lane>>3), chunk (lane&7)^(lane>>3)
    const int lrow = lane >> 3;
    const int lchk = (lane & 7) ^ lrow;
    const bf16* gA = Xb + (size_t)(m0 + wave * 8 + lrow) * IN + lchk * 8;
    const bf16* gB = Wb + (size_t)(o0 + wave * 8 + lrow) * IN + lchk * 8;

    for (int i = tid; i < 8 * KB; i += 512)
        sMask[i] = mask[(o0 >> 5) * KB + i];

    // ---- prologue: tiles 0 (buf0) and 1 (buf1), ungated; single drain ----
    STAGE_A(0, 0, 0, 0);  STAGE_A(0, 0, 1, 0);
    STAGE_A(0, 1, 0, 0);  STAGE_A(0, 1, 1, 0);
    STAGE_B(0, 0, 0, 0);  STAGE_B(0, 0, 1, 0);
    STAGE_B(0, 1, 0, 0);  STAGE_B(0, 1, 1, 0);
    STAGE_A(1, 0, 0, BK); STAGE_A(1, 0, 1, BK);
    STAGE_A(1, 1, 0, BK); STAGE_A(1, 1, 1, BK);
    STAGE_B(1, 0, 0, BK); STAGE_B(1, 0, 1, BK);
    STAGE_B(1, 1, 0, BK); STAGE_B(1, 1, 1, BK);
    __syncthreads();   // publishes sMask + tiles 0/1 (the only full drain)

    f32x4 acc[8][4] = {};
    const int mr0 = (wc * 2) * KB;       // mask row for j-pair {0,1}
    const int mr1 = mr0 + KB;            // mask row for j-pair {2,3}
    const int sq  = wave >> 2;           // stager's strip: +0/+1 within quarter

    for (int t = 0; t < NT; ++t) {
        const int c  = t & 1;
        const int cn = c ^ 1;
        const int t1 = (t + 1 < NT) ? t + 1 : 0;   // dummy wrap on last tile
        const size_t k1 = (size_t)t1 * BK;

        // ---- tile top: tile t fully landed; lead ~1 full tile => free ----
        asm volatile("s_waitcnt vmcnt(0)" ::: "memory");
        __builtin_amdgcn_s_barrier();
        __builtin_amdgcn_sched_barrier(0);   // no motion across tile boundary

        // ---- issue ALL of tile t+1's staging NOW (max latency lead) ----
        STAGE_A(cn, 0, 0, k1); STAGE_A(cn, 0, 1, k1);
        STAGE_A(cn, 1, 0, k1); STAGE_A(cn, 1, 1, k1);
        {   // B gated per 8-row strip (wave-uniform; dead strips never read)
            const int ca = 2 * t1, cbx = 2 * t1 + 1;
            #pragma unroll
            for (int H = 0; H < 2; ++H) {
                #pragma unroll
                for (int V = 0; V < 2; ++V) {
                    const int qrow = H * 4 + V * 2 + sq;
                    if (sMask[qrow * KB + ca] | sMask[qrow * KB + cbx])
                        STAGE_B(cn, H, V, k1);
                }
            }
        }

        const int mv00 = __builtin_amdgcn_readfirstlane(sMask[mr0 + 2 * t]);
        const int mv10 = __builtin_amdgcn_readfirstlane(sMask[mr1 + 2 * t]);
        const int mv01 = __builtin_amdgcn_readfirstlane(sMask[mr0 + 2 * t + 1]);
        const int mv11 = __builtin_amdgcn_readfirstlane(sMask[mr1 + 2 * t + 1]);

        const char* baseA = (const char*)sA[c][wr];
        const char* baseB = (const char*)sB[c][wc >> 1];
        short8 a[8];

        // ---- kk0: gated reads + gated MFMAs, free per-wave order ----
        if (mv00 | mv10) {
            #pragma unroll
            for (int i = 0; i < 8; ++i)
                a[i] = *(const short8*)(baseA + i * 2048 + rowA + cb0);
        }
        short8 b00a, b00b, b10a, b10b;
        if (mv00) {
            b00a = *(const short8*)(baseB + rowB + cb0);
            b00b = *(const short8*)(baseB + rowB + 2048 + cb0);
        }
        if (mv10) {
            b10a = *(const short8*)(baseB + rowB + 4096 + cb0);
            b10b = *(const short8*)(baseB + rowB + 6144 + cb0);
        }
        __builtin_amdgcn_s_setprio(1);
        if (mv00) MFMA_J2(0, a, b00a, b00b);
        if (mv10) MFMA_J2(2, a, b10a, b10b);
        __builtin_amdgcn_s_setprio(0);

        // ---- kk1 ----
        if (mv01 | mv11) {
            #pragma unroll
            for (int i = 0; i < 8; ++i)
                a[i] = *(const short8*)(baseA + i * 2048 + rowA + cb1);
        }
        short8 b01a, b01b, b11a, b11b;
        if (mv01) {
            b01a = *(const short8*)(baseB + rowB + cb1);
            b01b = *(const short8*)(baseB + rowB + 2048 + cb1);
        }
        if (mv11) {
            b11a = *(const short8*)(baseB + rowB + 4096 + cb1);
            b11b = *(const short8*)(baseB + rowB + 6144 + cb1);
        }
        __builtin_amdgcn_s_setprio(1);
        if (mv01) MFMA_J2(0, a, b01a, b01b);
        if (mv11) MFMA_J2(2, a, b11a, b11b);
        __builtin_amdgcn_s_setprio(0);
    }

    asm volatile("s_waitcnt vmcnt(0)" ::: "memory");  // no pending DMA at end

    // ---- epilogue: C/D layout col=lane&15, row=(lane>>4)*4+reg; fp32 out ----
    const int rbase = (lane >> 4) * 4;
    const int ccol  = lane & 15;
    #pragma unroll
    for (int j = 0; j < 4; ++j) {
        int o = o0 + wc * 64 + j * 16 + ccol;
        float bv = bias[o];
        #pragma unroll
        for (int i = 0; i < 8; ++i) {
            #pragma unroll
            for (int r = 0; r < 4; ++r) {
                int m = m0 + wr * 128 + i * 16 + rbase + r;
                out[(size_t)m * OUT + o] = acc[i][j][r] + bv;
            }
        }
    }
}

// ---------------- Fallback (round-2 single-pass, known-good) ----------------
#define FBM 128
#define FBO 128
#define FBK 64
#define LDK (FBK + 8)
__global__ __launch_bounds__(256, 2)
void bsl_fallback_kernel(const float* __restrict__ X, const float* __restrict__ W,
                         const float* __restrict__ bias, const int* __restrict__ mask,
                         float* __restrict__ out)
{
    __shared__ bf16 sA[FBM * LDK];
    __shared__ bf16 sB[FBO * LDK];
    const int tid = threadIdx.x;
    const int m0 = blockIdx.x * FBM, o0 = blockIdx.y * FBO;
    const int wave = tid >> 6, lane = tid & 63;
    const int wm = (wave & 1) * 64, wo = (wave >> 1) * 64;
    const int lm = lane & 15, lk = (lane >> 4) * 8;
    f32x4 acc[4][4] = {};
    for (int k0 = 0; k0 < IN; k0 += FBK) {
        #pragma unroll
        for (int v = 0; v < 8; ++v) {
            int e = (v * 256 + tid) * 4, row = e >> 6, col = e & 63;
            float4 d = *(const float4*)(X + (size_t)(m0 + row) * IN + (k0 + col));
            *(short4_t*)(sA + row * LDK + col) = cvt4_bf16(d.x, d.y, d.z, d.w);
        }
        #pragma unroll
        for (int v = 0; v < 8; ++v) {
            int e = (v * 256 + tid) * 4, row = e >> 6, col = e & 63;
            int mv = mask[((o0 + row) >> 5) * KB + ((k0 + col) >> 5)];
            short4_t p = {};
            if (mv != 0) {
                float4 d = *(const float4*)(W + (size_t)(o0 + row) * IN + (k0 + col));
                p = cvt4_bf16(d.x, d.y, d.z, d.w);
            }
            *(short4_t*)(sB + row * LDK + col) = p;
        }
        __syncthreads();
        #pragma unroll
        for (int kk = 0; kk < FBK; kk += 32) {
            short8 af[4], bfr[4];
            #pragma unroll
            for (int i = 0; i < 4; ++i)
                af[i] = *(const short8*)(sA + (wm + i * 16 + lm) * LDK + kk + lk);
            #pragma unroll
            for (int j = 0; j < 4; ++j)
                bfr[j] = *(const short8*)(sB + (wo + j * 16 + lm) * LDK + kk + lk);
            #pragma unroll
            for (int i = 0; i < 4; ++i)
                #pragma unroll
                for (int j = 0; j < 4; ++j)
                    acc[i][j] = __builtin_amdgcn_mfma_f32_16x16x32_bf16(
                        af[i], bfr[j], acc[i][j], 0, 0, 0);
        }
        __syncthreads();
    }
    const int rbase = (lane >> 4) * 4, ccol = lane & 15;
    #pragma unroll
    for (int j = 0; j < 4; ++j) {
        int o = o0 + wo + j * 16 + ccol;
        float bv = bias[o];
        #pragma unroll
        for (int i = 0; i < 4; ++i)
            #pragma unroll
            for (int r = 0; r < 4; ++r)
                out[(size_t)(m0 + wm + i * 16 + rbase + r) * OUT + o] = acc[i][j][r] + bv;
    }
}

extern "C" void kernel_launch(void* const* d_in, const int* in_sizes, int n_in,
                              void* d_out, int out_size, void* d_ws, size_t ws_size,
                              hipStream_t stream) {
    const float* x    = (const float*)d_in[0];   // (8192, 4096) fp32
    const float* w    = (const float*)d_in[1];   // (4096, 4096) fp32
    const float* bias = (const float*)d_in[2];   // (4096,) fp32
    const int*   mask = (const int*)  d_in[3];   // (128, 128) int32
    float* out = (float*)d_out;                  // (8192, 4096) fp32

    const size_t xb_bytes = (size_t)N_ROWS * IN * sizeof(bf16);  // 64 MB
    const size_t wb_bytes = (size_t)OUT * IN * sizeof(bf16);     // 32 MB

    if (ws_size >= xb_bytes + wb_bytes) {
        bf16* xb = (bf16*)d_ws;
        bf16* wb = (bf16*)((char*)d_ws + xb_bytes);
        const int xblk = (int)((N_ROWS * (size_t)IN) / 1024);    // 32768
        const int wblk = (int)((OUT * (size_t)IN) / 1024);       // 16384
        cvt_kernel<<<xblk + wblk, 256, 0, stream>>>(x, w, mask, xb, wb);
        dim3 grid(OUT / BO, N_ROWS / BM);        // (16, 32): o fast, m slow
        bsl_gemm256_kernel<<<grid, 512, 0, stream>>>(xb, wb, bias, mask, out);
    } else {
        dim3 grid(N_ROWS / FBM, OUT / FBO);
        bsl_fallback_kernel<<<grid, 256, 0, stream>>>(x, w, bias, mask, out);
    }
}